// Round 20
// baseline (1070.840 us; speedup 1.0000x reference)
//
#include <hip/hip_runtime.h>

typedef unsigned int u32;
typedef unsigned short u16;
typedef short short8 __attribute__((ext_vector_type(8)));
typedef float f32x4 __attribute__((ext_vector_type(4)));
typedef unsigned short us4 __attribute__((ext_vector_type(4)));

#define S_LEN 2048
#define BATCH 2
#define HID 4096
#define NH 32
#define HD 128
#define TRIH 12288

#define GCAST(p) ((const __attribute__((address_space(1))) u32*)(p))
#define LCAST(p) ((__attribute__((address_space(3))) u32*)(p))

static __device__ __forceinline__ u16 f2bf(float f) {
  union { float f; u32 u; } x; x.f = f;
  u32 u = x.u;
  u32 r = u + 0x7FFFu + ((u >> 16) & 1u);
  return (u16)(r >> 16);
}
static __device__ __forceinline__ float bf2f(u16 h) {
  union { u32 u; float f; } x; x.u = ((u32)h) << 16;
  return x.f;
}

// ---------------- convert fp32 -> bf16 ----------------
__global__ __launch_bounds__(256) void cvt_f32_bf16(const float* __restrict__ in,
                                                    u16* __restrict__ out, int n4) {
  int i = blockIdx.x * 256 + threadIdx.x;
  if (i >= n4) return;
  float4 v = ((const float4*)in)[i];
  us4 o;
  o.x = f2bf(v.x); o.y = f2bf(v.y); o.z = f2bf(v.z); o.w = f2bf(v.w);
  ((us4*)out)[i] = o;
}

// ------- transpose + convert, 64x64 tile, float4 reads / us4 writes -------
__global__ __launch_bounds__(256) void tr_cvt(const float* __restrict__ in,
                                              u16* __restrict__ out, int R, int C) {
  __shared__ float tile[64][65];
  int c0 = blockIdx.x * 64, r0 = blockIdx.y * 64;
  int tx = threadIdx.x;
  int rr = tx >> 4;              // 0..15
  int cc = (tx & 15) << 2;       // 0,4,...,60
#pragma unroll
  for (int it = 0; it < 4; ++it) {
    float4 v = *(const float4*)&in[(size_t)(r0 + rr + it * 16) * C + c0 + cc];
    tile[rr + it * 16][cc + 0] = v.x;
    tile[rr + it * 16][cc + 1] = v.y;
    tile[rr + it * 16][cc + 2] = v.z;
    tile[rr + it * 16][cc + 3] = v.w;
  }
  __syncthreads();
#pragma unroll
  for (int it = 0; it < 4; ++it) {
    int crow = rr + it * 16;
    us4 o;
    o.x = f2bf(tile[cc + 0][crow]);
    o.y = f2bf(tile[cc + 1][crow]);
    o.z = f2bf(tile[cc + 2][crow]);
    o.w = f2bf(tile[cc + 3][crow]);
    *(us4*)&out[(size_t)(c0 + crow) * R + r0 + cc] = o;
  }
}

// ================= 256x256 GEMM, 2-phase-per-K-tile + cross-phase A-prefetch =================
// C[M][N] = A[M][K] * Bt[N][K]^T, bf16 in, bf16/f32 out. K % 128 == 0.
// 512 threads = 8 waves (2M x 4N). LDS 128KB: A[2buf][2half][128][64], B same.
// LDS element (r,k) at r*64 + ((k>>3)^(r&7))*8 + (k&7) (chunk-XOR swizzle),
// via pre-swizzled global source (linear global_load_lds dest).
// ROUND-20: af2 (rows 64-127) ds_reads hoisted into the A-phase so the B-phase
// is pure-MFMA; the hoisted reads hide under A's 32 MFMAs + barrier (compiler
// emits the counted lgkmcnt at B's first consuming MFMA). af2's LDS source is
// only restaged after the B-close barrier (register-resident, consumed by then).
// Round-17 lesson: counted vmcnt(4) with 2-phase prefetch distance; never
// vmcnt(0) mid-loop. Seam = drain own loads THEN barrier.

template<int MQ, int NQ>
static __device__ __forceinline__ void mfma_quad(f32x4 (&acc)[8][4], short8 (&af)[4][2],
                                                 short8 (&bfr)[4][2]) {
#pragma unroll
  for (int ml = 0; ml < 4; ++ml)
#pragma unroll
    for (int nl = 0; nl < 2; ++nl) {
      acc[MQ*4+ml][NQ*2+nl] = __builtin_amdgcn_mfma_f32_16x16x32_bf16(
          af[ml][0], bfr[NQ*2+nl][0], acc[MQ*4+ml][NQ*2+nl], 0, 0, 0);
      acc[MQ*4+ml][NQ*2+nl] = __builtin_amdgcn_mfma_f32_16x16x32_bf16(
          af[ml][1], bfr[NQ*2+nl][1], acc[MQ*4+ml][NQ*2+nl], 0, 0, 0);
    }
}

template<int MQ>
static __device__ __forceinline__ void read_a(short8 (&af)[4][2], const u16* abase, int lane) {
#pragma unroll
  for (int ml = 0; ml < 4; ++ml) {
    int r = MQ*64 + ml*16 + (lane & 15);
#pragma unroll
    for (int kh = 0; kh < 2; ++kh) {
      int j = kh*4 + (lane >> 4);
      af[ml][kh] = *(const short8*)(abase + r*64 + ((j ^ (r & 7)) << 3));
    }
  }
}
template<int NQ>
static __device__ __forceinline__ void read_b(short8 (&bfr)[4][2], const u16* bbase,
                                              int rbase, int lane) {
#pragma unroll
  for (int nl = 0; nl < 2; ++nl) {
    int r = rbase + (NQ*2+nl)*16 + (lane & 15);
#pragma unroll
    for (int kh = 0; kh < 2; ++kh) {
      int j = kh*4 + (lane >> 4);
      bfr[NQ*2+nl][kh] = *(const short8*)(bbase + r*64 + ((j ^ (r & 7)) << 3));
    }
  }
}

#define PHASE_CLOSE() \
  __builtin_amdgcn_s_barrier(); \
  __builtin_amdgcn_sched_barrier(0);

#define SEAM_CLOSE(NSTR) \
  asm volatile("s_waitcnt vmcnt(" NSTR ")" ::: "memory"); \
  __builtin_amdgcn_s_barrier(); \
  __builtin_amdgcn_sched_barrier(0);

template<int OUTF32>
__global__ __launch_bounds__(512, 1) void gemm256(const u16* __restrict__ A,
                                                  const u16* __restrict__ Bt,
                                                  void* __restrict__ Cout,
                                                  int M, int N, int K, int nbm) {
  __shared__ __attribute__((aligned(16))) u16 lds[65536];  // 128KB
  const int tid = threadIdx.x, wave = tid >> 6, lane = tid & 63;
  const int wr = wave >> 2, wc = wave & 3;
  const int nwg = gridDim.x, wg = blockIdx.x, cpx = nwg >> 3;
  const int swz = (wg & 7) * cpx + (wg >> 3);
  const size_t tileM = (size_t)(swz % nbm) * 256;   // column-major: M fast (L2 B-panel reuse)
  const size_t tileN = (size_t)(swz / nbm) * 256;
  const int nIter = K >> 7;   // 2 K-tiles (BK=64) per iteration

  const int r_ = tid >> 3;                 // rows 0..63 (+64 for second load)
  const int gc_ = (tid & 7) ^ (r_ & 7);    // pre-swizzled global chunk

  const u16* Ag = A + tileM * K;
  const u16* Bg = Bt + tileN * K;

  f32x4 acc[8][4] = {};
  short8 af[4][2], af2[4][2], bfr[4][2];

  auto stageA = [&](int kt, int buf, int half) {
    const u16* g0 = Ag + (size_t)(half*128 + r_) * K + kt*64 + (gc_ << 3);
    u16* l = lds + buf*16384 + half*8192 + wave*512;
    __builtin_amdgcn_global_load_lds(GCAST(g0), LCAST(l), 16, 0, 0);
    __builtin_amdgcn_global_load_lds(GCAST(g0 + (size_t)64*K), LCAST(l + 4096), 16, 0, 0);
  };
  auto stageB = [&](int kt, int buf, int half) {
    const u16* g0 = Bg + (size_t)(half*128 + r_) * K + kt*64 + (gc_ << 3);
    u16* l = lds + 32768 + buf*16384 + half*8192 + wave*512;
    __builtin_amdgcn_global_load_lds(GCAST(g0), LCAST(l), 16, 0, 0);
    __builtin_amdgcn_global_load_lds(GCAST(g0 + (size_t)64*K), LCAST(l + 4096), 16, 0, 0);
  };

  const u16* a0 = lds + wr*8192;                       // A buf0 read base (wave's half)
  const u16* a1 = lds + 16384 + wr*8192;               // A buf1
  const u16* b0 = lds + 32768 + (wc >> 1)*8192;        // B buf0
  const u16* b1 = lds + 32768 + 16384 + (wc >> 1)*8192;// B buf1
  const int brb = (wc & 1) * 64;

  // prologue: tile0 (A+B) -> buf0, tile1 B -> buf1   (12 loads/thread in flight)
  stageA(0, 0, 0); stageA(0, 0, 1);
  stageB(0, 0, 0); stageB(0, 0, 1);
  stageB(1, 1, 0); stageB(1, 1, 1);
  // pre-loop seam: drain A0+B0 (8 oldest), then barrier
  SEAM_CLOSE("4")

  for (int i = 0; i < nIter; ++i) {
    const int t1 = 2*i + 1, t2 = 2*i + 2, t3 = 2*i + 3;
    const bool more = (i + 1 < nIter);

    // ---- Phase A0: tile 2i, buf0, quads (0,0)+(0,1); pre-read af2 for B0 ----
    read_a<0>(af, a0, lane);
    read_b<0>(bfr, b0, brb, lane);
    read_b<1>(bfr, b0, brb, lane);
    read_a<1>(af2, a0, lane);
    stageA(t1, 1, 0); stageA(t1, 1, 1);
    __builtin_amdgcn_s_setprio(1);
    mfma_quad<0, 0>(acc, af, bfr);
    mfma_quad<0, 1>(acc, af, bfr);
    __builtin_amdgcn_s_setprio(0);
    PHASE_CLOSE()

    // ---- Phase B0: tile 2i, buf0, quads (1,0)+(1,1) — pure MFMA ----
    if (more) { stageB(t2, 0, 0); stageB(t2, 0, 1); }
    __builtin_amdgcn_s_setprio(1);
    mfma_quad<1, 0>(acc, af2, bfr);
    mfma_quad<1, 1>(acc, af2, bfr);
    __builtin_amdgcn_s_setprio(0);
    if (more) { SEAM_CLOSE("4") } else { SEAM_CLOSE("0") }

    // ---- Phase A1: tile 2i+1, buf1, quads (0,0)+(0,1); pre-read af2 for B1 ----
    read_a<0>(af, a1, lane);
    read_b<0>(bfr, b1, brb, lane);
    read_b<1>(bfr, b1, brb, lane);
    read_a<1>(af2, a1, lane);
    if (more) { stageA(t2, 0, 0); stageA(t2, 0, 1); }
    __builtin_amdgcn_s_setprio(1);
    mfma_quad<0, 0>(acc, af, bfr);
    mfma_quad<0, 1>(acc, af, bfr);
    __builtin_amdgcn_s_setprio(0);
    PHASE_CLOSE()

    // ---- Phase B1: tile 2i+1, buf1, quads (1,0)+(1,1) — pure MFMA ----
    if (more) { stageB(t3, 1, 0); stageB(t3, 1, 1); }
    __builtin_amdgcn_s_setprio(1);
    mfma_quad<1, 0>(acc, af2, bfr);
    mfma_quad<1, 1>(acc, af2, bfr);
    __builtin_amdgcn_s_setprio(0);
    if (more) { SEAM_CLOSE("4") } else { PHASE_CLOSE() }
  }

  // epilogue: C write
  const int r0o = (lane >> 4) << 2, c0o = lane & 15;
#pragma unroll
  for (int m = 0; m < 8; ++m)
#pragma unroll
    for (int n = 0; n < 4; ++n)
#pragma unroll
      for (int rr = 0; rr < 4; ++rr) {
        size_t grow = tileM + wr*128 + m*16 + r0o + rr;
        size_t gcol = tileN + wc*64 + n*16 + c0o;
        if (OUTF32) ((float*)Cout)[grow * N + gcol] = acc[m][n][rr];
        else        ((u16*)Cout)[grow * N + gcol] = f2bf(acc[m][n][rr]);
      }
}

// ---------------- RoPE, vectorized: 8 (j, j+64) pairs per thread ----------------
__global__ __launch_bounds__(256) void rope_kernel(u16* __restrict__ qkv,
                                                   const int* __restrict__ pid) {
  int idx = blockIdx.x * 256 + threadIdx.x;   // 0 .. 2,097,151
  int row = idx >> 9;           // B*S row (512 threads per row)
  int rem = idx & 511;
  int which = rem >> 8;         // 0=q, 1=k
  int h = (rem >> 3) & 31;
  int j0 = (rem & 7) << 3;      // 0,8,...,56
  u16* p = qkv + (size_t)row * TRIH + which * HID + h * HD + j0;
  short8 lo = *(short8*)p;
  short8 hi = *(short8*)(p + 64);
  float pos = (float)pid[row];
  short8 olo, ohi;
#pragma unroll
  for (int i = 0; i < 8; ++i) {
    float x0 = bf2f((u16)lo[i]), x1 = bf2f((u16)hi[i]);
    float th = pos * expf(-(float)(j0 + i) * 0.14391156831212787f);  // ln(10000)/64
    float sn, cs;
    sincosf(th, &sn, &cs);
    olo[i] = (short)f2bf(x0 * cs - x1 * sn);
    ohi[i] = (short)f2bf(x1 * cs + x0 * sn);
  }
  *(short8*)p = olo;
  *(short8*)(p + 64) = ohi;
}

// ---------------- flash attention: qkv [B*S][3H] bf16 -> O [B*S][H] bf16 ----------------
// 8 waves, QBLK=128 (16 q-rows/wave), KVBLK=64, double-buffered K/V.
// SWAPPED QK^T (T12-lite): s[n] = mfma(kf, qf) computes S^T — each lane holds
// 16 values all for q-row (lane&15). Row max/sum = in-lane + 2 shfls.
// launch_bounds(512,2): never cap VGPR below live count (round-11 spill).
__global__ __launch_bounds__(512, 2) void attn_kernel(const u16* __restrict__ qkv,
                                                      u16* __restrict__ O) {
  const int bid = blockIdx.x;           // 0..1023
  const int qt = 15 - (bid >> 6);       // long blocks dispatched first (LPT)
  const int bh = bid & 63;
  const int b = bh >> 5, h = bh & 31;
  const int tid = threadIdx.x, wave = tid >> 6, lane = tid & 63;
  __shared__ u16 Ks[2][64 * 128];       // 32KB, XOR-swizzled
  __shared__ u16 VsT[2][128 * 64];      // 32KB, transposed + swizzled
  __shared__ u16 Ps[8][16 * 64];        // 16KB, per-wave
  const u16* base = qkv + (size_t)b * S_LEN * TRIH + h * HD;

  const int rbase = (lane >> 4) << 2;
  const int cbase = lane & 15;
  const int q_lo = qt * 128;
  const int wrow0 = q_lo + wave * 16;

  // Q fragments straight from global (once per block)
  short8 qf[4];
  {
    const u16* qrow = base + (size_t)(wrow0 + cbase) * TRIH;
#pragma unroll
    for (int f = 0; f < 4; ++f)
      qf[f] = *(const short8*)(qrow + ((f * 4 + (lane >> 4)) << 3));
  }

  const int tmax_w = 2 * qt + (wave >= 4 ? 1 : 0);
  const int tmax_b = 2 * qt + 1;

  float mrun = -1e30f, lrun = 0.f;      // per-lane state for q-row (wrow0+cbase)
  f32x4 accO[8] = {};

  short8 kreg[2], vreg[2];
  auto load_tile = [&](int t) {
    int kv = t << 6;
#pragma unroll
    for (int it = 0; it < 2; ++it) {
      int c = tid + it * 512;
      int row = c >> 4, ch = c & 15;
      const u16* src = base + (size_t)(kv + row) * TRIH + (ch << 3);
      kreg[it] = *(const short8*)(src + HID);
      vreg[it] = *(const short8*)(src + 2 * HID);
    }
  };
  auto write_tile = [&](int buf) {
#pragma unroll
    for (int it = 0; it < 2; ++it) {
      int c = tid + it * 512;
      int row = c >> 4, ch = c & 15;
      *(short8*)(Ks[buf] + row * 128 + ((ch ^ (row & 7)) << 3)) = kreg[it];
#pragma unroll
      for (int i = 0; i < 8; ++i) {
        int d = (ch << 3) + i;
        VsT[buf][d * 64 + (((row >> 3) ^ (ch & 7)) << 3) + (row & 7)] = (u16)vreg[it][i];
      }
    }
  };

  // prologue: tile0 -> buf0; tile1 into regs.
  load_tile(0);
  write_tile(0);
  load_tile(1);

  for (int t = 0; t <= tmax_b; ++t) {
    const int cur = t & 1;
    __syncthreads();   // buf[cur] writes visible; prev reads of buf[cur^1] done
    if (t < tmax_b) write_tile(cur ^ 1);
    if (t + 2 <= tmax_b) load_tile(t + 2);

    if (t > tmax_w) continue;   // fully-masked tile for this wave

    // S^T = K Q^T  (swapped operands: lane holds q-row = cbase, kv = n*16+rbase+r)
    f32x4 s[4] = {};
    __builtin_amdgcn_s_setprio(1);
#pragma unroll
    for (int n = 0; n < 4; ++n) {
      int krow = n * 16 + cbase;
#pragma unroll
      for (int f = 0; f < 4; ++f) {
        int ch = f * 4 + (lane >> 4);
        short8 kf = *(const short8*)(Ks[cur] + krow * 128 + ((ch ^ (krow & 7)) << 3));
        s[n] = __builtin_amdgcn_mfma_f32_16x16x32_bf16(kf, qf[f], s[n], 0, 0, 0);
      }
    }
    __builtin_amdgcn_s_setprio(0);
    const float scale = 0.08838834764831845f;
    const int kv0 = t << 6;
    const int qcol = wrow0 + cbase;
    if (t == tmax_w) {
#pragma unroll
      for (int n = 0; n < 4; ++n)
#pragma unroll
        for (int r = 0; r < 4; ++r) {
          int kvrow = kv0 + n * 16 + rbase + r;
          s[n][r] = (kvrow <= qcol) ? s[n][r] * scale : -1e30f;
        }
    } else {
#pragma unroll
      for (int n = 0; n < 4; ++n) s[n] *= scale;
    }

    // online softmax, in-lane (T12-lite) with defer-max (T13)
    float pmax = -1e30f;
#pragma unroll
    for (int n = 0; n < 4; ++n)
#pragma unroll
      for (int r = 0; r < 4; ++r) pmax = fmaxf(pmax, s[n][r]);
    pmax = fmaxf(pmax, __shfl_xor(pmax, 16));
    pmax = fmaxf(pmax, __shfl_xor(pmax, 32));

    if (__any(pmax > mrun + 8.0f)) {
      float mnew = fmaxf(mrun, pmax);
      float corr = __expf(mrun - mnew);
      float rs = 0.f;
#pragma unroll
      for (int n = 0; n < 4; ++n)
#pragma unroll
        for (int r = 0; r < 4; ++r) { float pv = __expf(s[n][r] - mnew); s[n][r] = pv; rs += pv; }
      rs += __shfl_xor(rs, 16); rs += __shfl_xor(rs, 32);
      lrun = lrun * corr + rs;
      mrun = mnew;
      float cq[4];
#pragma unroll
      for (int r = 0; r < 4; ++r) cq[r] = __shfl(corr, rbase + r);
#pragma unroll
      for (int nd = 0; nd < 8; ++nd)
#pragma unroll
        for (int r = 0; r < 4; ++r) accO[nd][r] *= cq[r];
    } else {
      float rs = 0.f;
#pragma unroll
      for (int n = 0; n < 4; ++n)
#pragma unroll
        for (int r = 0; r < 4; ++r) { float pv = __expf(s[n][r] - mrun); s[n][r] = pv; rs += pv; }
      rs += __shfl_xor(rs, 16); rs += __shfl_xor(rs, 32);
      lrun += rs;
    }

    // P -> LDS: element (q=cbase, kv=n*16+rbase+r) at q*64 + ((kv>>3)^(q&7))*8 + (kv&7)
    u16* Pw = (u16*)Ps[wave];
#pragma unroll
    for (int n = 0; n < 4; ++n)
#pragma unroll
      for (int r = 0; r < 4; ++r) {
        int kv = n * 16 + rbase + r;
        Pw[cbase * 64 + (((kv >> 3) ^ (cbase & 7)) << 3) + (kv & 7)] = f2bf(s[n][r]);
      }

    // O += P V
    short8 pa[2];
    {
      int prow = lane & 15;
#pragma unroll
      for (int f2 = 0; f2 < 2; ++f2) {
        int ch = f2 * 4 + (lane >> 4);
        pa[f2] = *(const short8*)(Pw + prow * 64 + ((ch ^ (prow & 7)) << 3));
      }
    }
    __builtin_amdgcn_s_setprio(1);
#pragma unroll
    for (int nd = 0; nd < 8; ++nd) {
      int drow = nd * 16 + cbase;
#pragma unroll
      for (int f2 = 0; f2 < 2; ++f2) {
        int ch = f2 * 4 + (lane >> 4);
        short8 vb = *(const short8*)(VsT[cur] + drow * 64 + ((ch ^ ((drow >> 3) & 7)) << 3));
        accO[nd] = __builtin_amdgcn_mfma_f32_16x16x32_bf16(pa[f2], vb, accO[nd], 0, 0, 0);
      }
    }
    __builtin_amdgcn_s_setprio(0);
  }

  // write O scaled by 1/l (broadcast l from softmax lanes to accO row layout)
  float lq[4];
#pragma unroll
  for (int r = 0; r < 4; ++r) lq[r] = __shfl(lrun, rbase + r);
#pragma unroll
  for (int nd = 0; nd < 8; ++nd)
#pragma unroll
    for (int r = 0; r < 4; ++r) {
      int qrow = wrow0 + rbase + r;
      int col = h * HD + nd * 16 + cbase;
      O[(size_t)(b * S_LEN + qrow) * HID + col] = f2bf(accO[nd][r] / lq[r]);
    }
}

extern "C" void kernel_launch(void* const* d_in, const int* in_sizes, int n_in,
                              void* d_out, int out_size, void* d_ws, size_t ws_size,
                              hipStream_t stream) {
  const float* hidden = (const float*)d_in[0];
  const float* w_qkv  = (const float*)d_in[1];
  const float* wo     = (const float*)d_in[2];
  const int*   pid    = (const int*)d_in[3];

  const size_t MB = 1024ull * 1024ull;
  u16* hb    = (u16*)d_ws;                        // 32MB  (later reused as O)
  u16* wqkvT = (u16*)((char*)d_ws + 32 * MB);     // 96MB  [12288][4096]
  u16* woT   = (u16*)((char*)d_ws + 128 * MB);    // 32MB  [4096][4096]
  u16* qkvb  = (u16*)((char*)d_ws + 160 * MB);    // 96MB  [4096][12288]
  u16* Obuf  = hb;                                // 32MB  [4096][4096]

  cvt_f32_bf16<<<16384, 256, 0, stream>>>(hidden, hb, (BATCH * S_LEN * HID) / 4);
  tr_cvt<<<dim3(TRIH / 64, HID / 64), 256, 0, stream>>>(w_qkv, wqkvT, HID, TRIH);
  tr_cvt<<<dim3(HID / 64, HID / 64), 256, 0, stream>>>(wo, woT, HID, HID);

  gemm256<0><<<768, 512, 0, stream>>>(hb, wqkvT, qkvb, BATCH * S_LEN, TRIH, HID, 16);

  rope_kernel<<<(BATCH * S_LEN * 2 * NH * 8) / 256, 256, 0, stream>>>(qkvb, pid);

  attn_kernel<<<1024, 512, 0, stream>>>(qkvb, Obuf);

  gemm256<1><<<256, 512, 0, stream>>>(Obuf, woT, d_out, BATCH * S_LEN, HID, HID, 16);
}

// Round 21
// 725.503 us; speedup vs baseline: 1.4760x; 1.4760x over previous
//
#include <hip/hip_runtime.h>

typedef unsigned int u32;
typedef unsigned short u16;
typedef short short8 __attribute__((ext_vector_type(8)));
typedef float f32x4 __attribute__((ext_vector_type(4)));
typedef unsigned short us4 __attribute__((ext_vector_type(4)));

#define S_LEN 2048
#define BATCH 2
#define HID 4096
#define NH 32
#define HD 128
#define TRIH 12288

#define GCAST(p) ((const __attribute__((address_space(1))) u32*)(p))
#define LCAST(p) ((__attribute__((address_space(3))) u32*)(p))

static __device__ __forceinline__ u16 f2bf(float f) {
  union { float f; u32 u; } x; x.f = f;
  u32 u = x.u;
  u32 r = u + 0x7FFFu + ((u >> 16) & 1u);
  return (u16)(r >> 16);
}
static __device__ __forceinline__ float bf2f(u16 h) {
  union { u32 u; float f; } x; x.u = ((u32)h) << 16;
  return x.f;
}

// ---------------- convert fp32 -> bf16 ----------------
__global__ __launch_bounds__(256) void cvt_f32_bf16(const float* __restrict__ in,
                                                    u16* __restrict__ out, int n4) {
  int i = blockIdx.x * 256 + threadIdx.x;
  if (i >= n4) return;
  float4 v = ((const float4*)in)[i];
  us4 o;
  o.x = f2bf(v.x); o.y = f2bf(v.y); o.z = f2bf(v.z); o.w = f2bf(v.w);
  ((us4*)out)[i] = o;
}

// ------- transpose + convert, 64x64 tile, float4 reads / us4 writes -------
__global__ __launch_bounds__(256) void tr_cvt(const float* __restrict__ in,
                                              u16* __restrict__ out, int R, int C) {
  __shared__ float tile[64][65];
  int c0 = blockIdx.x * 64, r0 = blockIdx.y * 64;
  int tx = threadIdx.x;
  int rr = tx >> 4;              // 0..15
  int cc = (tx & 15) << 2;       // 0,4,...,60
#pragma unroll
  for (int it = 0; it < 4; ++it) {
    float4 v = *(const float4*)&in[(size_t)(r0 + rr + it * 16) * C + c0 + cc];
    tile[rr + it * 16][cc + 0] = v.x;
    tile[rr + it * 16][cc + 1] = v.y;
    tile[rr + it * 16][cc + 2] = v.z;
    tile[rr + it * 16][cc + 3] = v.w;
  }
  __syncthreads();
#pragma unroll
  for (int it = 0; it < 4; ++it) {
    int crow = rr + it * 16;
    us4 o;
    o.x = f2bf(tile[cc + 0][crow]);
    o.y = f2bf(tile[cc + 1][crow]);
    o.z = f2bf(tile[cc + 2][crow]);
    o.w = f2bf(tile[cc + 3][crow]);
    *(us4*)&out[(size_t)(c0 + crow) * R + r0 + cc] = o;
  }
}

// ================= 256x256 GEMM, 2-phase-per-K-tile (round-15 structure) =================
// C[M][N] = A[M][K] * Bt[N][K]^T, bf16 in, bf16/f32 out. K % 128 == 0.
// 512 threads = 8 waves (2M x 4N). LDS 128KB: A[2buf][2half][128][64], B same.
// LDS element (r,k) at r*64 + ((k>>3)^(r&7))*8 + (k&7) (chunk-XOR swizzle),
// via pre-swizzled global source (linear global_load_lds dest).
// Round-17 lesson: 1-barrier merge with vmcnt(0) exposes HBM latency (385us).
// Round-20 lesson: cross-barrier af2 register prefetch -> scratch spill
// (WRITE_SIZE 99->278MB, 665us). This 2-phase + counted vmcnt(4) structure is
// the measured optimum (336us, MfmaUtil 57%).

template<int MQ, int NQ>
static __device__ __forceinline__ void mfma_quad(f32x4 (&acc)[8][4], short8 (&af)[4][2],
                                                 short8 (&bfr)[4][2]) {
#pragma unroll
  for (int ml = 0; ml < 4; ++ml)
#pragma unroll
    for (int nl = 0; nl < 2; ++nl) {
      acc[MQ*4+ml][NQ*2+nl] = __builtin_amdgcn_mfma_f32_16x16x32_bf16(
          af[ml][0], bfr[NQ*2+nl][0], acc[MQ*4+ml][NQ*2+nl], 0, 0, 0);
      acc[MQ*4+ml][NQ*2+nl] = __builtin_amdgcn_mfma_f32_16x16x32_bf16(
          af[ml][1], bfr[NQ*2+nl][1], acc[MQ*4+ml][NQ*2+nl], 0, 0, 0);
    }
}

template<int MQ>
static __device__ __forceinline__ void read_a(short8 (&af)[4][2], const u16* abase, int lane) {
#pragma unroll
  for (int ml = 0; ml < 4; ++ml) {
    int r = MQ*64 + ml*16 + (lane & 15);
#pragma unroll
    for (int kh = 0; kh < 2; ++kh) {
      int j = kh*4 + (lane >> 4);
      af[ml][kh] = *(const short8*)(abase + r*64 + ((j ^ (r & 7)) << 3));
    }
  }
}
template<int NQ>
static __device__ __forceinline__ void read_b(short8 (&bfr)[4][2], const u16* bbase,
                                              int rbase, int lane) {
#pragma unroll
  for (int nl = 0; nl < 2; ++nl) {
    int r = rbase + (NQ*2+nl)*16 + (lane & 15);
#pragma unroll
    for (int kh = 0; kh < 2; ++kh) {
      int j = kh*4 + (lane >> 4);
      bfr[NQ*2+nl][kh] = *(const short8*)(bbase + r*64 + ((j ^ (r & 7)) << 3));
    }
  }
}

#define PHASE_CLOSE() \
  __builtin_amdgcn_s_barrier(); \
  __builtin_amdgcn_sched_barrier(0);

#define SEAM_CLOSE(NSTR) \
  asm volatile("s_waitcnt vmcnt(" NSTR ")" ::: "memory"); \
  __builtin_amdgcn_s_barrier(); \
  __builtin_amdgcn_sched_barrier(0);

template<int OUTF32>
__global__ __launch_bounds__(512, 1) void gemm256(const u16* __restrict__ A,
                                                  const u16* __restrict__ Bt,
                                                  void* __restrict__ Cout,
                                                  int M, int N, int K, int nbm) {
  __shared__ __attribute__((aligned(16))) u16 lds[65536];  // 128KB
  const int tid = threadIdx.x, wave = tid >> 6, lane = tid & 63;
  const int wr = wave >> 2, wc = wave & 3;
  const int nwg = gridDim.x, wg = blockIdx.x, cpx = nwg >> 3;
  const int swz = (wg & 7) * cpx + (wg >> 3);
  const size_t tileM = (size_t)(swz % nbm) * 256;   // column-major: M fast (L2 B-panel reuse)
  const size_t tileN = (size_t)(swz / nbm) * 256;
  const int nIter = K >> 7;   // 2 K-tiles (BK=64) per iteration

  const int r_ = tid >> 3;                 // rows 0..63 (+64 for second load)
  const int gc_ = (tid & 7) ^ (r_ & 7);    // pre-swizzled global chunk

  const u16* Ag = A + tileM * K;
  const u16* Bg = Bt + tileN * K;

  f32x4 acc[8][4] = {};
  short8 af[4][2], bfr[4][2];

  auto stageA = [&](int kt, int buf, int half) {
    const u16* g0 = Ag + (size_t)(half*128 + r_) * K + kt*64 + (gc_ << 3);
    u16* l = lds + buf*16384 + half*8192 + wave*512;
    __builtin_amdgcn_global_load_lds(GCAST(g0), LCAST(l), 16, 0, 0);
    __builtin_amdgcn_global_load_lds(GCAST(g0 + (size_t)64*K), LCAST(l + 4096), 16, 0, 0);
  };
  auto stageB = [&](int kt, int buf, int half) {
    const u16* g0 = Bg + (size_t)(half*128 + r_) * K + kt*64 + (gc_ << 3);
    u16* l = lds + 32768 + buf*16384 + half*8192 + wave*512;
    __builtin_amdgcn_global_load_lds(GCAST(g0), LCAST(l), 16, 0, 0);
    __builtin_amdgcn_global_load_lds(GCAST(g0 + (size_t)64*K), LCAST(l + 4096), 16, 0, 0);
  };

  const u16* a0 = lds + wr*8192;                       // A buf0 read base (wave's half)
  const u16* a1 = lds + 16384 + wr*8192;               // A buf1
  const u16* b0 = lds + 32768 + (wc >> 1)*8192;        // B buf0
  const u16* b1 = lds + 32768 + 16384 + (wc >> 1)*8192;// B buf1
  const int brb = (wc & 1) * 64;

  // prologue: tile0 (A+B) -> buf0, tile1 B -> buf1   (12 loads/thread in flight)
  stageA(0, 0, 0); stageA(0, 0, 1);
  stageB(0, 0, 0); stageB(0, 0, 1);
  stageB(1, 1, 0); stageB(1, 1, 1);
  // pre-loop seam: drain A0+B0 (8 oldest), then barrier
  SEAM_CLOSE("4")

  for (int i = 0; i < nIter; ++i) {
    const int t1 = 2*i + 1, t2 = 2*i + 2, t3 = 2*i + 3;
    const bool more = (i + 1 < nIter);

    // ---- Phase A0: tile 2i, buf0, quads (0,0)+(0,1) ----
    read_a<0>(af, a0, lane);
    read_b<0>(bfr, b0, brb, lane);
    read_b<1>(bfr, b0, brb, lane);
    stageA(t1, 1, 0); stageA(t1, 1, 1);
    __builtin_amdgcn_s_setprio(1);
    mfma_quad<0, 0>(acc, af, bfr);
    mfma_quad<0, 1>(acc, af, bfr);
    __builtin_amdgcn_s_setprio(0);
    PHASE_CLOSE()

    // ---- Phase B0: tile 2i, buf0, quads (1,0)+(1,1) ----
    read_a<1>(af, a0, lane);
    if (more) { stageB(t2, 0, 0); stageB(t2, 0, 1); }
    __builtin_amdgcn_s_setprio(1);
    mfma_quad<1, 0>(acc, af, bfr);
    mfma_quad<1, 1>(acc, af, bfr);
    __builtin_amdgcn_s_setprio(0);
    if (more) { SEAM_CLOSE("4") } else { SEAM_CLOSE("0") }

    // ---- Phase A1: tile 2i+1, buf1, quads (0,0)+(0,1) ----
    read_a<0>(af, a1, lane);
    read_b<0>(bfr, b1, brb, lane);
    read_b<1>(bfr, b1, brb, lane);
    if (more) { stageA(t2, 0, 0); stageA(t2, 0, 1); }
    __builtin_amdgcn_s_setprio(1);
    mfma_quad<0, 0>(acc, af, bfr);
    mfma_quad<0, 1>(acc, af, bfr);
    __builtin_amdgcn_s_setprio(0);
    PHASE_CLOSE()

    // ---- Phase B1: tile 2i+1, buf1, quads (1,0)+(1,1) ----
    read_a<1>(af, a1, lane);
    if (more) { stageB(t3, 1, 0); stageB(t3, 1, 1); }
    __builtin_amdgcn_s_setprio(1);
    mfma_quad<1, 0>(acc, af, bfr);
    mfma_quad<1, 1>(acc, af, bfr);
    __builtin_amdgcn_s_setprio(0);
    if (more) { SEAM_CLOSE("4") } else { PHASE_CLOSE() }
  }

  // epilogue: C write
  const int r0o = (lane >> 4) << 2, c0o = lane & 15;
#pragma unroll
  for (int m = 0; m < 8; ++m)
#pragma unroll
    for (int n = 0; n < 4; ++n)
#pragma unroll
      for (int rr = 0; rr < 4; ++rr) {
        size_t grow = tileM + wr*128 + m*16 + r0o + rr;
        size_t gcol = tileN + wc*64 + n*16 + c0o;
        if (OUTF32) ((float*)Cout)[grow * N + gcol] = acc[m][n][rr];
        else        ((u16*)Cout)[grow * N + gcol] = f2bf(acc[m][n][rr]);
      }
}

// ---------------- RoPE, vectorized: 8 (j, j+64) pairs per thread ----------------
__global__ __launch_bounds__(256) void rope_kernel(u16* __restrict__ qkv,
                                                   const int* __restrict__ pid) {
  int idx = blockIdx.x * 256 + threadIdx.x;   // 0 .. 2,097,151
  int row = idx >> 9;           // B*S row (512 threads per row)
  int rem = idx & 511;
  int which = rem >> 8;         // 0=q, 1=k
  int h = (rem >> 3) & 31;
  int j0 = (rem & 7) << 3;      // 0,8,...,56
  u16* p = qkv + (size_t)row * TRIH + which * HID + h * HD + j0;
  short8 lo = *(short8*)p;
  short8 hi = *(short8*)(p + 64);
  float pos = (float)pid[row];
  short8 olo, ohi;
#pragma unroll
  for (int i = 0; i < 8; ++i) {
    float x0 = bf2f((u16)lo[i]), x1 = bf2f((u16)hi[i]);
    float th = pos * expf(-(float)(j0 + i) * 0.14391156831212787f);  // ln(10000)/64
    float sn, cs;
    sincosf(th, &sn, &cs);
    olo[i] = (short)f2bf(x0 * cs - x1 * sn);
    ohi[i] = (short)f2bf(x1 * cs + x0 * sn);
  }
  *(short8*)p = olo;
  *(short8*)(p + 64) = ohi;
}

// ---------------- flash attention: qkv [B*S][3H] bf16 -> O [B*S][H] bf16 ----------------
// 8 waves, QBLK=128 (16 q-rows/wave), KVBLK=64, double-buffered K/V.
// SWAPPED QK^T (T12-lite): s[n] = mfma(kf, qf) computes S^T — each lane holds
// 16 values all for q-row (lane&15). Row max/sum = in-lane + 2 shfls.
// launch_bounds(512,2): never cap VGPR below live count (round-11 spill).
__global__ __launch_bounds__(512, 2) void attn_kernel(const u16* __restrict__ qkv,
                                                      u16* __restrict__ O) {
  const int bid = blockIdx.x;           // 0..1023
  const int qt = 15 - (bid >> 6);       // long blocks dispatched first (LPT)
  const int bh = bid & 63;
  const int b = bh >> 5, h = bh & 31;
  const int tid = threadIdx.x, wave = tid >> 6, lane = tid & 63;
  __shared__ u16 Ks[2][64 * 128];       // 32KB, XOR-swizzled
  __shared__ u16 VsT[2][128 * 64];      // 32KB, transposed + swizzled
  __shared__ u16 Ps[8][16 * 64];        // 16KB, per-wave
  const u16* base = qkv + (size_t)b * S_LEN * TRIH + h * HD;

  const int rbase = (lane >> 4) << 2;
  const int cbase = lane & 15;
  const int q_lo = qt * 128;
  const int wrow0 = q_lo + wave * 16;

  // Q fragments straight from global (once per block)
  short8 qf[4];
  {
    const u16* qrow = base + (size_t)(wrow0 + cbase) * TRIH;
#pragma unroll
    for (int f = 0; f < 4; ++f)
      qf[f] = *(const short8*)(qrow + ((f * 4 + (lane >> 4)) << 3));
  }

  const int tmax_w = 2 * qt + (wave >= 4 ? 1 : 0);
  const int tmax_b = 2 * qt + 1;

  float mrun = -1e30f, lrun = 0.f;      // per-lane state for q-row (wrow0+cbase)
  f32x4 accO[8] = {};

  short8 kreg[2], vreg[2];
  auto load_tile = [&](int t) {
    int kv = t << 6;
#pragma unroll
    for (int it = 0; it < 2; ++it) {
      int c = tid + it * 512;
      int row = c >> 4, ch = c & 15;
      const u16* src = base + (size_t)(kv + row) * TRIH + (ch << 3);
      kreg[it] = *(const short8*)(src + HID);
      vreg[it] = *(const short8*)(src + 2 * HID);
    }
  };
  auto write_tile = [&](int buf) {
#pragma unroll
    for (int it = 0; it < 2; ++it) {
      int c = tid + it * 512;
      int row = c >> 4, ch = c & 15;
      *(short8*)(Ks[buf] + row * 128 + ((ch ^ (row & 7)) << 3)) = kreg[it];
#pragma unroll
      for (int i = 0; i < 8; ++i) {
        int d = (ch << 3) + i;
        VsT[buf][d * 64 + (((row >> 3) ^ (ch & 7)) << 3) + (row & 7)] = (u16)vreg[it][i];
      }
    }
  };

  // prologue: tile0 -> buf0; tile1 into regs.
  load_tile(0);
  write_tile(0);
  load_tile(1);

  for (int t = 0; t <= tmax_b; ++t) {
    const int cur = t & 1;
    __syncthreads();   // buf[cur] writes visible; prev reads of buf[cur^1] done
    if (t < tmax_b) write_tile(cur ^ 1);
    if (t + 2 <= tmax_b) load_tile(t + 2);

    if (t > tmax_w) continue;   // fully-masked tile for this wave

    // S^T = K Q^T  (swapped operands: lane holds q-row = cbase, kv = n*16+rbase+r)
    f32x4 s[4] = {};
    __builtin_amdgcn_s_setprio(1);
#pragma unroll
    for (int n = 0; n < 4; ++n) {
      int krow = n * 16 + cbase;
#pragma unroll
      for (int f = 0; f < 4; ++f) {
        int ch = f * 4 + (lane >> 4);
        short8 kf = *(const short8*)(Ks[cur] + krow * 128 + ((ch ^ (krow & 7)) << 3));
        s[n] = __builtin_amdgcn_mfma_f32_16x16x32_bf16(kf, qf[f], s[n], 0, 0, 0);
      }
    }
    __builtin_amdgcn_s_setprio(0);
    const float scale = 0.08838834764831845f;
    const int kv0 = t << 6;
    const int qcol = wrow0 + cbase;
    if (t == tmax_w) {
#pragma unroll
      for (int n = 0; n < 4; ++n)
#pragma unroll
        for (int r = 0; r < 4; ++r) {
          int kvrow = kv0 + n * 16 + rbase + r;
          s[n][r] = (kvrow <= qcol) ? s[n][r] * scale : -1e30f;
        }
    } else {
#pragma unroll
      for (int n = 0; n < 4; ++n) s[n] *= scale;
    }

    // online softmax, in-lane (T12-lite) with defer-max (T13)
    float pmax = -1e30f;
#pragma unroll
    for (int n = 0; n < 4; ++n)
#pragma unroll
      for (int r = 0; r < 4; ++r) pmax = fmaxf(pmax, s[n][r]);
    pmax = fmaxf(pmax, __shfl_xor(pmax, 16));
    pmax = fmaxf(pmax, __shfl_xor(pmax, 32));

    if (__any(pmax > mrun + 8.0f)) {
      float mnew = fmaxf(mrun, pmax);
      float corr = __expf(mrun - mnew);
      float rs = 0.f;
#pragma unroll
      for (int n = 0; n < 4; ++n)
#pragma unroll
        for (int r = 0; r < 4; ++r) { float pv = __expf(s[n][r] - mnew); s[n][r] = pv; rs += pv; }
      rs += __shfl_xor(rs, 16); rs += __shfl_xor(rs, 32);
      lrun = lrun * corr + rs;
      mrun = mnew;
      float cq[4];
#pragma unroll
      for (int r = 0; r < 4; ++r) cq[r] = __shfl(corr, rbase + r);
#pragma unroll
      for (int nd = 0; nd < 8; ++nd)
#pragma unroll
        for (int r = 0; r < 4; ++r) accO[nd][r] *= cq[r];
    } else {
      float rs = 0.f;
#pragma unroll
      for (int n = 0; n < 4; ++n)
#pragma unroll
        for (int r = 0; r < 4; ++r) { float pv = __expf(s[n][r] - mrun); s[n][r] = pv; rs += pv; }
      rs += __shfl_xor(rs, 16); rs += __shfl_xor(rs, 32);
      lrun += rs;
    }

    // P -> LDS: element (q=cbase, kv=n*16+rbase+r) at q*64 + ((kv>>3)^(q&7))*8 + (kv&7)
    u16* Pw = (u16*)Ps[wave];
#pragma unroll
    for (int n = 0; n < 4; ++n)
#pragma unroll
      for (int r = 0; r < 4; ++r) {
        int kv = n * 16 + rbase + r;
        Pw[cbase * 64 + (((kv >> 3) ^ (cbase & 7)) << 3) + (kv & 7)] = f2bf(s[n][r]);
      }

    // O += P V
    short8 pa[2];
    {
      int prow = lane & 15;
#pragma unroll
      for (int f2 = 0; f2 < 2; ++f2) {
        int ch = f2 * 4 + (lane >> 4);
        pa[f2] = *(const short8*)(Pw + prow * 64 + ((ch ^ (prow & 7)) << 3));
      }
    }
    __builtin_amdgcn_s_setprio(1);
#pragma unroll
    for (int nd = 0; nd < 8; ++nd) {
      int drow = nd * 16 + cbase;
#pragma unroll
      for (int f2 = 0; f2 < 2; ++f2) {
        int ch = f2 * 4 + (lane >> 4);
        short8 vb = *(const short8*)(VsT[cur] + drow * 64 + ((ch ^ ((drow >> 3) & 7)) << 3));
        accO[nd] = __builtin_amdgcn_mfma_f32_16x16x32_bf16(pa[f2], vb, accO[nd], 0, 0, 0);
      }
    }
    __builtin_amdgcn_s_setprio(0);
  }

  // write O scaled by 1/l (broadcast l from softmax lanes to accO row layout)
  float lq[4];
#pragma unroll
  for (int r = 0; r < 4; ++r) lq[r] = __shfl(lrun, rbase + r);
#pragma unroll
  for (int nd = 0; nd < 8; ++nd)
#pragma unroll
    for (int r = 0; r < 4; ++r) {
      int qrow = wrow0 + rbase + r;
      int col = h * HD + nd * 16 + cbase;
      O[(size_t)(b * S_LEN + qrow) * HID + col] = f2bf(accO[nd][r] / lq[r]);
    }
}

extern "C" void kernel_launch(void* const* d_in, const int* in_sizes, int n_in,
                              void* d_out, int out_size, void* d_ws, size_t ws_size,
                              hipStream_t stream) {
  const float* hidden = (const float*)d_in[0];
  const float* w_qkv  = (const float*)d_in[1];
  const float* wo     = (const float*)d_in[2];
  const int*   pid    = (const int*)d_in[3];

  const size_t MB = 1024ull * 1024ull;
  u16* hb    = (u16*)d_ws;                        // 32MB  (later reused as O)
  u16* wqkvT = (u16*)((char*)d_ws + 32 * MB);     // 96MB  [12288][4096]
  u16* woT   = (u16*)((char*)d_ws + 128 * MB);    // 32MB  [4096][4096]
  u16* qkvb  = (u16*)((char*)d_ws + 160 * MB);    // 96MB  [4096][12288]
  u16* Obuf  = hb;                                // 32MB  [4096][4096]

  cvt_f32_bf16<<<16384, 256, 0, stream>>>(hidden, hb, (BATCH * S_LEN * HID) / 4);
  tr_cvt<<<dim3(TRIH / 64, HID / 64), 256, 0, stream>>>(w_qkv, wqkvT, HID, TRIH);
  tr_cvt<<<dim3(HID / 64, HID / 64), 256, 0, stream>>>(wo, woT, HID, HID);

  gemm256<0><<<768, 512, 0, stream>>>(hb, wqkvT, qkvb, BATCH * S_LEN, TRIH, HID, 16);

  rope_kernel<<<(BATCH * S_LEN * 2 * NH * 8) / 256, 256, 0, stream>>>(qkvb, pid);

  attn_kernel<<<1024, 512, 0, stream>>>(qkvb, Obuf);

  gemm256<1><<<256, 512, 0, stream>>>(Obuf, woT, d_out, BATCH * S_LEN, HID, HID, 16);
}